// Round 1
// baseline (732.760 us; speedup 1.0000x reference)
//
#include <hip/hip_runtime.h>
#include <hip/hip_bf16.h>

// Shapes (fixed by the problem): B=32, S=2048, E=1024, U=1024. M = B*S = 65536.
// score[m] = v . tanh( lhs[m,:] @ (W+U)^T )   -- one bf16 MFMA GEMM, fused epilogue
// out[b,:] = sum_s softmax_s(masked score)[s] * lhs[b,s,:]

typedef short bf16x8 __attribute__((ext_vector_type(8)));
typedef float f32x4  __attribute__((ext_vector_type(4)));

static __device__ __forceinline__ unsigned short f2bf(float f) {
    unsigned int x = __float_as_uint(f);
    unsigned int r = x + 0x7FFFu + ((x >> 16) & 1u);   // RNE
    return (unsigned short)(r >> 16);
}

// ---------------- K0: Wsum = bf16(W+U), zero score & out ----------------
__global__ __launch_bounds__(256)
void prep_kernel(const float* __restrict__ W, const float* __restrict__ U,
                 unsigned short* __restrict__ wsum,
                 float* __restrict__ score, float* __restrict__ out) {
    int g = blockIdx.x * 256 + threadIdx.x;          // 262144 threads
    int i4 = g * 4;                                   // 1,048,576 wsum elems
    float4 w = *(const float4*)&W[i4];
    float4 u = *(const float4*)&U[i4];
    ushort4 h;
    h.x = f2bf(w.x + u.x); h.y = f2bf(w.y + u.y);
    h.z = f2bf(w.z + u.z); h.w = f2bf(w.w + u.w);
    *(ushort4*)&wsum[i4] = h;
    if (g < 65536) score[g] = 0.0f;
    if (g < 32768) out[g] = 0.0f;
}

// ---------------- K1: fused score GEMM ----------------
// A = lhs [M=65536, K=1024] fp32 row-major; B = wsum [N=1024, K=1024] bf16 row-major.
// Block: 128x128 tile, 256 threads (4 waves, each 64x64 = 4x4 MFMA 16x16x32 frags).
#define BM 128
#define BN 128
#define BK 32
#define LDSS 40   // 32 + 8 pad (keeps 16B alignment of q*16 offsets; 80B row stride)

__global__ __launch_bounds__(256)
void score_gemm_kernel(const float* __restrict__ A, const unsigned short* __restrict__ Bw,
                       const float* __restrict__ v, float* __restrict__ score) {
    const int K = 1024;
    __shared__ __align__(16) unsigned short As[BM][LDSS];
    __shared__ __align__(16) unsigned short Bs[BN][LDSS];

    const int m0 = (int)blockIdx.x * BM;    // 512 m-tiles
    const int n0 = (int)blockIdx.y * BN;    // 8 n-tiles

    const int t    = threadIdx.x;
    const int lane = t & 63;
    const int wave = t >> 6;
    const int wm   = (wave & 1) * 64;
    const int wn   = (wave >> 1) * 64;
    const int ml   = lane & 15;
    const int q    = lane >> 4;

    f32x4 acc[4][4];
#pragma unroll
    for (int i = 0; i < 4; ++i)
#pragma unroll
        for (int j = 0; j < 4; ++j)
            acc[i][j] = (f32x4){0.f, 0.f, 0.f, 0.f};

    const int sr = t >> 3;         // 0..31 (row within pass)
    const int sc = (t & 7) * 4;    // k offset 0,4,...,28

    for (int kk = 0; kk < K; kk += BK) {
        // stage A (fp32 -> bf16): 128 rows x 32 k
#pragma unroll
        for (int p = 0; p < 4; ++p) {
            int r = sr + p * 32;
            float4 va = *(const float4*)&A[(size_t)(m0 + r) * K + kk + sc];
            ushort4 h;
            h.x = f2bf(va.x); h.y = f2bf(va.y); h.z = f2bf(va.z); h.w = f2bf(va.w);
            *(ushort4*)&As[r][sc] = h;
        }
        // stage B (already bf16)
#pragma unroll
        for (int p = 0; p < 4; ++p) {
            int r = sr + p * 32;
            ushort4 vb = *(const ushort4*)&Bw[(size_t)(n0 + r) * K + kk + sc];
            *(ushort4*)&Bs[r][sc] = vb;
        }
        __syncthreads();

        bf16x8 af[4], bf[4];
#pragma unroll
        for (int i = 0; i < 4; ++i)
            af[i] = *(const bf16x8*)&As[wm + i * 16 + ml][q * 8];
#pragma unroll
        for (int j = 0; j < 4; ++j)
            bf[j] = *(const bf16x8*)&Bs[wn + j * 16 + ml][q * 8];
#pragma unroll
        for (int i = 0; i < 4; ++i)
#pragma unroll
            for (int j = 0; j < 4; ++j)
                acc[i][j] = __builtin_amdgcn_mfma_f32_16x16x32_bf16(af[i], bf[j], acc[i][j], 0, 0, 0);
        __syncthreads();
    }

    // Epilogue: score[m] += sum_n v[n] * tanh(P[m,n]) over this block's n-range.
    // D layout (16x16x32): col(n) = lane&15, row(m) = (lane>>4)*4 + reg.
    float vw[4];
#pragma unroll
    for (int j = 0; j < 4; ++j)
        vw[j] = v[n0 + wn + j * 16 + ml];

#pragma unroll
    for (int i = 0; i < 4; ++i) {
#pragma unroll
        for (int r = 0; r < 4; ++r) {
            float val = 0.f;
#pragma unroll
            for (int j = 0; j < 4; ++j)
                val += tanhf(acc[i][j][r]) * vw[j];
            // reduce across the 16 n-lanes of this quad
#pragma unroll
            for (int off = 8; off > 0; off >>= 1)
                val += __shfl_xor(val, off, 64);
            if (ml == 0) {
                int m = m0 + wm + i * 16 + q * 4 + r;
                atomicAdd(&score[m], val);
            }
        }
    }
}

// ---------------- K2: masked softmax over S per batch row ----------------
__global__ __launch_bounds__(256)
void softmax_kernel(const float* __restrict__ score, const int* __restrict__ mask,
                    float* __restrict__ alpha) {
    const int S = 2048;
    int b = blockIdx.x;
    int t = threadIdx.x;
    __shared__ float red[8];

    float sc[8];
    int vd[8];
    float mx = -1e30f;
#pragma unroll
    for (int i = 0; i < 8; ++i) {
        int s = i * 256 + t;
        vd[i] = mask[b * S + s];
        sc[i] = score[b * S + s];
        if (vd[i]) mx = fmaxf(mx, sc[i]);
    }
#pragma unroll
    for (int off = 32; off > 0; off >>= 1)
        mx = fmaxf(mx, __shfl_xor(mx, off, 64));
    if ((t & 63) == 0) red[t >> 6] = mx;
    __syncthreads();
    mx = fmaxf(fmaxf(red[0], red[1]), fmaxf(red[2], red[3]));

    float e[8];
    float sum = 0.f;
#pragma unroll
    for (int i = 0; i < 8; ++i) {
        e[i] = vd[i] ? __expf(sc[i] - mx) : 0.f;
        sum += e[i];
    }
#pragma unroll
    for (int off = 32; off > 0; off >>= 1)
        sum += __shfl_xor(sum, off, 64);
    if ((t & 63) == 0) red[4 + (t >> 6)] = sum;
    __syncthreads();
    float inv = 1.0f / (red[4] + red[5] + red[6] + red[7]);
#pragma unroll
    for (int i = 0; i < 8; ++i)
        alpha[b * S + i * 256 + t] = e[i] * inv;
}

// ---------------- K3: out[b,:] += sum_s alpha[b,s] * lhs[b,s,:] ----------------
__global__ __launch_bounds__(256)
void wsum_kernel(const float* __restrict__ lhs, const float* __restrict__ alpha,
                 float* __restrict__ out) {
    const int S = 2048, E = 1024;
    int b = blockIdx.x >> 3;
    int seg = blockIdx.x & 7;
    int t = threadIdx.x;
    int s0 = seg * 256;
    const float* base = lhs + ((size_t)b * S + s0) * E + t * 4;
    const float* ap = alpha + b * S + s0;
    float4 acc = {0.f, 0.f, 0.f, 0.f};
    for (int s = 0; s < 256; ++s) {
        float a = ap[s];
        if (a != 0.f) {                     // masked rows: alpha == 0 exactly, skip the load
            float4 x = *(const float4*)(base + (size_t)s * E);
            acc.x += a * x.x; acc.y += a * x.y; acc.z += a * x.z; acc.w += a * x.w;
        }
    }
    float* o = out + b * E + t * 4;
    atomicAdd(o + 0, acc.x);
    atomicAdd(o + 1, acc.y);
    atomicAdd(o + 2, acc.z);
    atomicAdd(o + 3, acc.w);
}

extern "C" void kernel_launch(void* const* d_in, const int* in_sizes, int n_in,
                              void* d_out, int out_size, void* d_ws, size_t ws_size,
                              hipStream_t stream) {
    const float* lhs  = (const float*)d_in[0];   // [32,2048,1024] fp32
    const int*   mask = (const int*)d_in[1];     // [32,2048] int32
    const float* W    = (const float*)d_in[2];   // [1024,1024] fp32
    const float* Um   = (const float*)d_in[3];   // [1024,1024] fp32
    const float* v    = (const float*)d_in[4];   // [1024] fp32
    float* out = (float*)d_out;                  // [32,1024] fp32

    unsigned short* wsum = (unsigned short*)d_ws;                       // 2 MB bf16
    float* score = (float*)((char*)d_ws + 2u * 1024u * 1024u);          // 256 KB
    float* alpha = (float*)((char*)d_ws + 2u * 1024u * 1024u + 256u * 1024u); // 256 KB

    prep_kernel<<<1024, 256, 0, stream>>>(W, Um, wsum, score, out);
    dim3 g1(512, 8);
    score_gemm_kernel<<<g1, 256, 0, stream>>>(lhs, wsum, v, score);
    softmax_kernel<<<32, 256, 0, stream>>>(score, mask, alpha);
    wsum_kernel<<<256, 256, 0, stream>>>(lhs, alpha, out);
}

// Round 3
// 611.490 us; speedup vs baseline: 1.1983x; 1.1983x over previous
//
#include <hip/hip_runtime.h>
#include <hip/hip_bf16.h>

// Shapes (fixed): B=32, S=2048, E=1024, U=1024. M = B*S = 65536.
// score[m] = v . tanh( lhs[m,:] @ (W+U)^T )   -- one bf16 MFMA GEMM, fused epilogue
// out[b,:] = sum_s softmax_s(masked score)[s] * lhs[b,s,:]
//
// ws layout: wsum bf16 [0, 2MB) | score [2MB, +256KB) | alpha [+256KB) | Ab bf16 [2.5MB, +128MB)

typedef short bf16x8 __attribute__((ext_vector_type(8)));
typedef float f32x4  __attribute__((ext_vector_type(4)));
typedef unsigned short u16x8 __attribute__((ext_vector_type(8)));

static __device__ __forceinline__ unsigned short f2bf(float f) {
    unsigned int x = __float_as_uint(f);
    unsigned int r = x + 0x7FFFu + ((x >> 16) & 1u);   // RNE
    return (unsigned short)(r >> 16);
}

static __device__ __forceinline__ float fast_tanh(float x) {
    // tanh(x) = 1 - 2/(1+e^{2x});  e^{2x} = 2^(x*2*log2(e))
    float e = __builtin_amdgcn_exp2f(x * 2.885390082f);   // v_exp_f32
    float r = __builtin_amdgcn_rcpf(e + 1.0f);
    return __builtin_fmaf(-2.0f, r, 1.0f);
}

// ---------------- K0: Wsum = bf16(W+U), zero score & out ----------------
__global__ __launch_bounds__(256)
void prep_kernel(const float* __restrict__ W, const float* __restrict__ U,
                 unsigned short* __restrict__ wsum,
                 float* __restrict__ score, float* __restrict__ out) {
    int g = blockIdx.x * 256 + threadIdx.x;          // 262144 threads
    int i4 = g * 4;                                   // 1,048,576 wsum elems
    float4 w = *(const float4*)&W[i4];
    float4 u = *(const float4*)&U[i4];
    ushort4 h;
    h.x = f2bf(w.x + u.x); h.y = f2bf(w.y + u.y);
    h.z = f2bf(w.z + u.z); h.w = f2bf(w.w + u.w);
    *(ushort4*)&wsum[i4] = h;
    if (g < 65536) score[g] = 0.0f;
    if (g < 32768) out[g] = 0.0f;
}

// ---------------- K0b: Ab = bf16(lhs) ----------------
__global__ __launch_bounds__(256)
void convert_kernel(const float* __restrict__ lhs, unsigned short* __restrict__ Ab) {
    size_t g = (size_t)blockIdx.x * 256 + threadIdx.x;   // 8,388,608 threads
    size_t i8 = g * 8;
    float4 a = *(const float4*)&lhs[i8];
    float4 b = *(const float4*)&lhs[i8 + 4];
    u16x8 h;
    h[0] = f2bf(a.x); h[1] = f2bf(a.y); h[2] = f2bf(a.z); h[3] = f2bf(a.w);
    h[4] = f2bf(b.x); h[5] = f2bf(b.y); h[6] = f2bf(b.z); h[7] = f2bf(b.w);
    *(u16x8*)&Ab[i8] = h;
}

// ---------------- K1: fused score GEMM (bf16 A, global_load_lds staging) ----------------
// A = Ab [M,K=1024] bf16 row-major; B = wsum [N=1024,K] bf16 row-major.
// Block 128x128, 256 thr (4 waves, 64x64 each = 4x4 MFMA 16x16x32 frags). BK=32.
// LDS: unpadded [128][32] bf16 (8 KB each) -- required by global_load_lds lane layout.
__global__ __launch_bounds__(256)
void score_gemm_bf16(const unsigned short* __restrict__ Ab,
                     const unsigned short* __restrict__ Bw,
                     const float* __restrict__ v, float* __restrict__ score) {
    const int K = 1024;
    __shared__ __align__(16) unsigned short As[128 * 32];
    __shared__ __align__(16) unsigned short Bs[128 * 32];

    const int n0 = (int)blockIdx.x * 128;   // 8  (fast-varying -> A-slab reuse in L2/L3)
    const int m0 = (int)blockIdx.y * 128;   // 512

    const int t    = threadIdx.x;
    const int lane = t & 63;
    const int wave = t >> 6;
    const int wm   = (wave & 1) * 64;
    const int wn   = (wave >> 1) * 64;
    const int ml   = lane & 15;
    const int q    = lane >> 4;

    f32x4 acc[4][4];
#pragma unroll
    for (int i = 0; i < 4; ++i)
#pragma unroll
        for (int j = 0; j < 4; ++j)
            acc[i][j] = (f32x4){0.f, 0.f, 0.f, 0.f};

    // Staging: tile = 128 rows x 32 k bf16 = 8 KB = 512 x 16B chunks.
    // chunk c -> row c>>2, k-offset (c&3)*8. Wave w, pass p covers c = (p*4+w)*64 + lane.
    // LDS dest is wave-uniform base + lane*16 (global_load_lds HW rule).
    const int c0 = wave * 64 + lane;
    const int c1 = (4 + wave) * 64 + lane;
    const unsigned short* ga0 = Ab + (size_t)(m0 + (c0 >> 2)) * K + (c0 & 3) * 8;
    const unsigned short* ga1 = Ab + (size_t)(m0 + (c1 >> 2)) * K + (c1 & 3) * 8;
    const unsigned short* gb0 = Bw + (size_t)(n0 + (c0 >> 2)) * K + (c0 & 3) * 8;
    const unsigned short* gb1 = Bw + (size_t)(n0 + (c1 >> 2)) * K + (c1 & 3) * 8;
    unsigned short* la0 = &As[wave * 512];        // byte offset wave*1024
    unsigned short* la1 = &As[(4 + wave) * 512];
    unsigned short* lb0 = &Bs[wave * 512];
    unsigned short* lb1 = &Bs[(4 + wave) * 512];

    for (int kk = 0; kk < K; kk += 32) {
        __builtin_amdgcn_global_load_lds((const __attribute__((address_space(1))) unsigned int*)ga0,
                                         (__attribute__((address_space(3))) unsigned int*)la0, 16, 0, 0);
        __builtin_amdgcn_global_load_lds((const __attribute__((address_space(1))) unsigned int*)ga1,
                                         (__attribute__((address_space(3))) unsigned int*)la1, 16, 0, 0);
        __builtin_amdgcn_global_load_lds((const __attribute__((address_space(1))) unsigned int*)gb0,
                                         (__attribute__((address_space(3))) unsigned int*)lb0, 16, 0, 0);
        __builtin_amdgcn_global_load_lds((const __attribute__((address_space(1))) unsigned int*)gb1,
                                         (__attribute__((address_space(3))) unsigned int*)lb1, 16, 0, 0);
        ga0 += 32; ga1 += 32; gb0 += 32; gb1 += 32;
        __syncthreads();

        bf16x8 af[4], bf[4];
#pragma unroll
        for (int i = 0; i < 4; ++i)
            af[i] = *(const bf16x8*)&As[(wm + i * 16 + ml) * 32 + q * 8];
#pragma unroll
        for (int j = 0; j < 4; ++j)
            bf[j] = *(const bf16x8*)&Bs[(wn + j * 16 + ml) * 32 + q * 8];
#pragma unroll
        for (int i = 0; i < 4; ++i)
#pragma unroll
            for (int j = 0; j < 4; ++j)
                acc[i][j] = __builtin_amdgcn_mfma_f32_16x16x32_bf16(af[i], bf[j], acc[i][j], 0, 0, 0);
        __syncthreads();
    }

    // Epilogue: score[m] += sum_n v[n]*tanh(P[m,n]).  D layout: col=lane&15, row=q*4+reg.
    float vw[4];
#pragma unroll
    for (int j = 0; j < 4; ++j)
        vw[j] = v[n0 + wn + j * 16 + ml];

#pragma unroll
    for (int i = 0; i < 4; ++i) {
#pragma unroll
        for (int r = 0; r < 4; ++r) {
            float val = 0.f;
#pragma unroll
            for (int j = 0; j < 4; ++j)
                val += fast_tanh(acc[i][j][r]) * vw[j];
#pragma unroll
            for (int off = 8; off > 0; off >>= 1)
                val += __shfl_xor(val, off, 64);
            if (ml == 0) {
                int m = m0 + wm + i * 16 + q * 4 + r;
                atomicAdd(&score[m], val);
            }
        }
    }
}

// ---------------- K1-fallback: fp32-staged GEMM (if ws too small for Ab) ----------------
#define LDSS 40
__global__ __launch_bounds__(256)
void score_gemm_f32stage(const float* __restrict__ A, const unsigned short* __restrict__ Bw,
                         const float* __restrict__ v, float* __restrict__ score) {
    const int K = 1024;
    __shared__ __align__(16) unsigned short As[128][LDSS];
    __shared__ __align__(16) unsigned short Bs[128][LDSS];
    const int n0 = (int)blockIdx.x * 128;
    const int m0 = (int)blockIdx.y * 128;
    const int t = threadIdx.x, lane = t & 63, wave = t >> 6;
    const int wm = (wave & 1) * 64, wn = (wave >> 1) * 64;
    const int ml = lane & 15, q = lane >> 4;
    f32x4 acc[4][4];
#pragma unroll
    for (int i = 0; i < 4; ++i)
#pragma unroll
        for (int j = 0; j < 4; ++j) acc[i][j] = (f32x4){0.f,0.f,0.f,0.f};
    const int sr = t >> 3, sc = (t & 7) * 4;
    for (int kk = 0; kk < K; kk += 32) {
#pragma unroll
        for (int p = 0; p < 4; ++p) {
            int r = sr + p * 32;
            float4 va = *(const float4*)&A[(size_t)(m0 + r) * K + kk + sc];
            ushort4 h; h.x = f2bf(va.x); h.y = f2bf(va.y); h.z = f2bf(va.z); h.w = f2bf(va.w);
            *(ushort4*)&As[r][sc] = h;
            ushort4 vb = *(const ushort4*)&Bw[(size_t)(n0 + r) * K + kk + sc];
            *(ushort4*)&Bs[r][sc] = vb;
        }
        __syncthreads();
        bf16x8 af[4], bf[4];
#pragma unroll
        for (int i = 0; i < 4; ++i) af[i] = *(const bf16x8*)&As[wm + i * 16 + ml][q * 8];
#pragma unroll
        for (int j = 0; j < 4; ++j) bf[j] = *(const bf16x8*)&Bs[wn + j * 16 + ml][q * 8];
#pragma unroll
        for (int i = 0; i < 4; ++i)
#pragma unroll
            for (int j = 0; j < 4; ++j)
                acc[i][j] = __builtin_amdgcn_mfma_f32_16x16x32_bf16(af[i], bf[j], acc[i][j], 0, 0, 0);
        __syncthreads();
    }
    float vw[4];
#pragma unroll
    for (int j = 0; j < 4; ++j) vw[j] = v[n0 + wn + j * 16 + ml];
#pragma unroll
    for (int i = 0; i < 4; ++i)
#pragma unroll
        for (int r = 0; r < 4; ++r) {
            float val = 0.f;
#pragma unroll
            for (int j = 0; j < 4; ++j) val += fast_tanh(acc[i][j][r]) * vw[j];
#pragma unroll
            for (int off = 8; off > 0; off >>= 1) val += __shfl_xor(val, off, 64);
            if (ml == 0) atomicAdd(&score[m0 + wm + i * 16 + q * 4 + r], val);
        }
}

// ---------------- K2: masked softmax over S per batch row ----------------
__global__ __launch_bounds__(256)
void softmax_kernel(const float* __restrict__ score, const int* __restrict__ mask,
                    float* __restrict__ alpha) {
    const int S = 2048;
    int b = blockIdx.x;
    int t = threadIdx.x;
    __shared__ float red[8];
    float sc[8];
    int vd[8];
    float mx = -1e30f;
#pragma unroll
    for (int i = 0; i < 8; ++i) {
        int s = i * 256 + t;
        vd[i] = mask[b * S + s];
        sc[i] = score[b * S + s];
        if (vd[i]) mx = fmaxf(mx, sc[i]);
    }
#pragma unroll
    for (int off = 32; off > 0; off >>= 1)
        mx = fmaxf(mx, __shfl_xor(mx, off, 64));
    if ((t & 63) == 0) red[t >> 6] = mx;
    __syncthreads();
    mx = fmaxf(fmaxf(red[0], red[1]), fmaxf(red[2], red[3]));
    float e[8];
    float sum = 0.f;
#pragma unroll
    for (int i = 0; i < 8; ++i) {
        e[i] = vd[i] ? __expf(sc[i] - mx) : 0.f;
        sum += e[i];
    }
#pragma unroll
    for (int off = 32; off > 0; off >>= 1)
        sum += __shfl_xor(sum, off, 64);
    if ((t & 63) == 0) red[4 + (t >> 6)] = sum;
    __syncthreads();
    float inv = 1.0f / (red[4] + red[5] + red[6] + red[7]);
#pragma unroll
    for (int i = 0; i < 8; ++i)
        alpha[b * S + i * 256 + t] = e[i] * inv;
}

// ---------------- K3: out[b,:] += sum_s alpha[b,s] * lhs[b,s,:] ----------------
__global__ __launch_bounds__(256)
void wsum_kernel(const float* __restrict__ lhs, const float* __restrict__ alpha,
                 float* __restrict__ out) {
    const int S = 2048, E = 1024;
    int b = blockIdx.x >> 6;          // 32 batches x 64 segments = 2048 blocks
    int seg = blockIdx.x & 63;
    int t = threadIdx.x;
    int s0 = seg * 32;
    const float* base = lhs + ((size_t)b * S + s0) * E + t * 4;
    const float* ap = alpha + b * S + s0;
    float4 acc = {0.f, 0.f, 0.f, 0.f};
#pragma unroll 4
    for (int s = 0; s < 32; ++s) {
        float a = ap[s];
        if (a != 0.f) {               // masked rows: alpha == 0 exactly, skip the load
            float4 x = *(const float4*)(base + (size_t)s * E);
            acc.x += a * x.x; acc.y += a * x.y; acc.z += a * x.z; acc.w += a * x.w;
        }
    }
    float* o = out + b * E + t * 4;
    atomicAdd(o + 0, acc.x);
    atomicAdd(o + 1, acc.y);
    atomicAdd(o + 2, acc.z);
    atomicAdd(o + 3, acc.w);
}

extern "C" void kernel_launch(void* const* d_in, const int* in_sizes, int n_in,
                              void* d_out, int out_size, void* d_ws, size_t ws_size,
                              hipStream_t stream) {
    const float* lhs  = (const float*)d_in[0];   // [32,2048,1024] fp32
    const int*   mask = (const int*)d_in[1];     // [32,2048] int32
    const float* W    = (const float*)d_in[2];   // [1024,1024] fp32
    const float* Um   = (const float*)d_in[3];   // [1024,1024] fp32
    const float* v    = (const float*)d_in[4];   // [1024] fp32
    float* out = (float*)d_out;                  // [32,1024] fp32

    unsigned short* wsum = (unsigned short*)d_ws;                               // 2 MB
    float* score = (float*)((char*)d_ws + 2u * 1024u * 1024u);                  // 256 KB
    float* alpha = (float*)((char*)d_ws + 2u * 1024u * 1024u + 256u * 1024u);   // 256 KB
    unsigned short* Ab = (unsigned short*)((char*)d_ws + 2560u * 1024u);        // 128 MB
    const size_t need = 2560ull * 1024ull + 65536ull * 1024ull * 2ull;

    prep_kernel<<<1024, 256, 0, stream>>>(W, Um, wsum, score, out);
    if (ws_size >= need) {
        convert_kernel<<<32768, 256, 0, stream>>>(lhs, Ab);
        dim3 g1(8, 512);
        score_gemm_bf16<<<g1, 256, 0, stream>>>(Ab, wsum, v, score);
    } else {
        dim3 g1(8, 512);
        score_gemm_f32stage<<<g1, 256, 0, stream>>>(lhs, wsum, v, score);
    }
    softmax_kernel<<<32, 256, 0, stream>>>(score, mask, alpha);
    wsum_kernel<<<2048, 256, 0, stream>>>(lhs, alpha, out);
}

// Round 4
// 515.434 us; speedup vs baseline: 1.4216x; 1.1864x over previous
//
#include <hip/hip_runtime.h>
#include <hip/hip_bf16.h>

// Shapes (fixed): B=32, S=2048, E=1024, U=1024. M = B*S = 65536.
// score[m] = v . tanh( lhs[m,:] @ (W+U)^T )  -- bf16 MFMA GEMM on COMPACTED valid rows
// out[b,:] = sum_s softmax_s(masked score)[s] * lhs[b,s,:]
//
// ws: wsum bf16 [0,2MB) | score [2MB,+256KB) | alpha [+256KB) | ridx u16 [2.5MB,+128KB)
//     | cnt i32 [2.625MB,+128B) | Ab bf16 [2.75MB,+128MB)

typedef short bf16x8 __attribute__((ext_vector_type(8)));
typedef float f32x4  __attribute__((ext_vector_type(4)));
typedef unsigned short u16x8 __attribute__((ext_vector_type(8)));

static __device__ __forceinline__ unsigned short f2bf(float f) {
    unsigned int x = __float_as_uint(f);
    unsigned int r = x + 0x7FFFu + ((x >> 16) & 1u);   // RNE
    return (unsigned short)(r >> 16);
}

static __device__ __forceinline__ float fast_tanh(float x) {
    float e = __builtin_amdgcn_exp2f(x * 2.885390082f);   // e^{2x}
    float r = __builtin_amdgcn_rcpf(e + 1.0f);
    return __builtin_fmaf(-2.0f, r, 1.0f);
}

// ---------------- K0: Wsum = bf16(W+U), zero score/alpha/out ----------------
__global__ __launch_bounds__(256)
void prep_kernel(const float* __restrict__ W, const float* __restrict__ U,
                 unsigned short* __restrict__ wsum,
                 float* __restrict__ score, float* __restrict__ alpha,
                 float* __restrict__ out) {
    int g = blockIdx.x * 256 + threadIdx.x;          // 262144 threads
    int i4 = g * 4;
    float4 w = *(const float4*)&W[i4];
    float4 u = *(const float4*)&U[i4];
    ushort4 h;
    h.x = f2bf(w.x + u.x); h.y = f2bf(w.y + u.y);
    h.z = f2bf(w.z + u.z); h.w = f2bf(w.w + u.w);
    *(ushort4*)&wsum[i4] = h;
    if (g < 65536) { score[g] = 0.0f; alpha[g] = 0.0f; }
    if (g < 32768) out[g] = 0.0f;
}

// ---------------- K1: per-batch valid-row index (block scan) ----------------
__global__ __launch_bounds__(256)
void index_kernel(const int* __restrict__ mask, unsigned short* __restrict__ ridx,
                  int* __restrict__ cnt) {
    int b = blockIdx.x, t = threadIdx.x;
    const int* mrow = mask + b * 2048;
    int m[8], c = 0;
#pragma unroll
    for (int j = 0; j < 8; ++j) { m[j] = mrow[t * 8 + j]; c += (m[j] != 0); }
    __shared__ int sc[256];
    sc[t] = c;
    __syncthreads();
    for (int off = 1; off < 256; off <<= 1) {
        int v = (t >= off) ? sc[t - off] : 0;
        __syncthreads();
        sc[t] += v;
        __syncthreads();
    }
    int base = sc[t] - c;
    unsigned short* rb = ridx + b * 2048;
#pragma unroll
    for (int j = 0; j < 8; ++j)
        if (m[j]) rb[base++] = (unsigned short)(t * 8 + j);
    if (t == 255) cnt[b] = sc[255];
}

// ---------------- K2: gather valid rows -> bf16 compact (zero-pad to x128) ----------------
// grid (512, 32): 4 rows/block, 64 threads x 16 elems per row.
__global__ __launch_bounds__(256)
void gather_convert(const float* __restrict__ lhs, const unsigned short* __restrict__ ridx,
                    const int* __restrict__ cnt, unsigned short* __restrict__ Ab) {
    int b = blockIdx.y;
    int c = cnt[b];
    int cpad = (c + 127) & ~127;
    int r = blockIdx.x * 4 + (threadIdx.x >> 6);
    int lt = threadIdx.x & 63;
    if (r >= cpad) return;
    unsigned short* dst = Ab + ((size_t)b * 2048 + r) * 1024 + lt * 16;
    if (r < c) {
        int s = ridx[b * 2048 + r];
        const float* src = lhs + ((size_t)b * 2048 + s) * 1024 + lt * 16;
        float4 a0 = *(const float4*)(src + 0);
        float4 a1 = *(const float4*)(src + 4);
        float4 a2 = *(const float4*)(src + 8);
        float4 a3 = *(const float4*)(src + 12);
        u16x8 h0, h1;
        h0[0] = f2bf(a0.x); h0[1] = f2bf(a0.y); h0[2] = f2bf(a0.z); h0[3] = f2bf(a0.w);
        h0[4] = f2bf(a1.x); h0[5] = f2bf(a1.y); h0[6] = f2bf(a1.z); h0[7] = f2bf(a1.w);
        h1[0] = f2bf(a2.x); h1[1] = f2bf(a2.y); h1[2] = f2bf(a2.z); h1[3] = f2bf(a2.w);
        h1[4] = f2bf(a3.x); h1[5] = f2bf(a3.y); h1[6] = f2bf(a3.z); h1[7] = f2bf(a3.w);
        *(u16x8*)(dst + 0) = h0;
        *(u16x8*)(dst + 8) = h1;
    } else {
        u16x8 z = (u16x8){0,0,0,0,0,0,0,0};
        *(u16x8*)(dst + 0) = z;
        *(u16x8*)(dst + 8) = z;
    }
}

// ---------------- K3: fused score GEMM on compact rows ----------------
// A = Ab [b*2048 + r][K=1024] bf16; B = wsum [N=1024,K] bf16. 128x128 tile, BK=32.
__global__ __launch_bounds__(256)
void score_gemm_bf16(const unsigned short* __restrict__ Ab,
                     const unsigned short* __restrict__ Bw,
                     const float* __restrict__ v, const int* __restrict__ cnt,
                     float* __restrict__ score) {
    const int K = 1024;
    __shared__ __align__(16) unsigned short As[128 * 32];
    __shared__ __align__(16) unsigned short Bs[128 * 32];

    const int tile = (int)blockIdx.y;          // 512 = 32 batches x 16 m-tiles
    const int b    = tile >> 4;
    const int lm0  = (tile & 15) << 7;
    const int c    = cnt[b];
    if (lm0 >= ((c + 127) & ~127)) return;     // beyond this batch's padded rows
    const int m0   = (b << 11) + lm0;
    const int n0   = (int)blockIdx.x * 128;    // 8 n-tiles (fast-varying)

    const int t    = threadIdx.x;
    const int lane = t & 63;
    const int wave = t >> 6;
    const int wm   = (wave & 1) * 64;
    const int wn   = (wave >> 1) * 64;
    const int ml   = lane & 15;
    const int q    = lane >> 4;

    f32x4 acc[4][4];
#pragma unroll
    for (int i = 0; i < 4; ++i)
#pragma unroll
        for (int j = 0; j < 4; ++j)
            acc[i][j] = (f32x4){0.f, 0.f, 0.f, 0.f};

    // global_load_lds staging: tile = 128 rows x 32 k bf16 = 512 x 16B chunks.
    const int c0 = wave * 64 + lane;
    const int c1 = (4 + wave) * 64 + lane;
    const unsigned short* ga0 = Ab + (size_t)(m0 + (c0 >> 2)) * K + (c0 & 3) * 8;
    const unsigned short* ga1 = Ab + (size_t)(m0 + (c1 >> 2)) * K + (c1 & 3) * 8;
    const unsigned short* gb0 = Bw + (size_t)(n0 + (c0 >> 2)) * K + (c0 & 3) * 8;
    const unsigned short* gb1 = Bw + (size_t)(n0 + (c1 >> 2)) * K + (c1 & 3) * 8;
    unsigned short* la0 = &As[wave * 512];
    unsigned short* la1 = &As[(4 + wave) * 512];
    unsigned short* lb0 = &Bs[wave * 512];
    unsigned short* lb1 = &Bs[(4 + wave) * 512];

    for (int kk = 0; kk < K; kk += 32) {
        __builtin_amdgcn_global_load_lds((const __attribute__((address_space(1))) unsigned int*)ga0,
                                         (__attribute__((address_space(3))) unsigned int*)la0, 16, 0, 0);
        __builtin_amdgcn_global_load_lds((const __attribute__((address_space(1))) unsigned int*)ga1,
                                         (__attribute__((address_space(3))) unsigned int*)la1, 16, 0, 0);
        __builtin_amdgcn_global_load_lds((const __attribute__((address_space(1))) unsigned int*)gb0,
                                         (__attribute__((address_space(3))) unsigned int*)lb0, 16, 0, 0);
        __builtin_amdgcn_global_load_lds((const __attribute__((address_space(1))) unsigned int*)gb1,
                                         (__attribute__((address_space(3))) unsigned int*)lb1, 16, 0, 0);
        ga0 += 32; ga1 += 32; gb0 += 32; gb1 += 32;
        __syncthreads();

        bf16x8 af[4], bf[4];
#pragma unroll
        for (int i = 0; i < 4; ++i)
            af[i] = *(const bf16x8*)&As[(wm + i * 16 + ml) * 32 + q * 8];
#pragma unroll
        for (int j = 0; j < 4; ++j)
            bf[j] = *(const bf16x8*)&Bs[(wn + j * 16 + ml) * 32 + q * 8];
#pragma unroll
        for (int i = 0; i < 4; ++i)
#pragma unroll
            for (int j = 0; j < 4; ++j)
                acc[i][j] = __builtin_amdgcn_mfma_f32_16x16x32_bf16(af[i], bf[j], acc[i][j], 0, 0, 0);
        __syncthreads();
    }

    // score[m] += sum_n v[n]*tanh(P[m,n]).  D layout: col=lane&15, row=q*4+reg.
    float vw[4];
#pragma unroll
    for (int j = 0; j < 4; ++j)
        vw[j] = v[n0 + wn + j * 16 + ml];

#pragma unroll
    for (int i = 0; i < 4; ++i) {
#pragma unroll
        for (int r = 0; r < 4; ++r) {
            float val = 0.f;
#pragma unroll
            for (int j = 0; j < 4; ++j)
                val += fast_tanh(acc[i][j][r]) * vw[j];
#pragma unroll
            for (int off = 8; off > 0; off >>= 1)
                val += __shfl_xor(val, off, 64);
            if (ml == 0)
                atomicAdd(&score[m0 + wm + i * 16 + q * 4 + r], val);
        }
    }
}

// ---------------- K3-fallback: fp32-staged GEMM over ALL rows (small ws) ----------------
#define LDSS 40
__global__ __launch_bounds__(256)
void score_gemm_f32stage(const float* __restrict__ A, const unsigned short* __restrict__ Bw,
                         const float* __restrict__ v, float* __restrict__ score) {
    const int K = 1024;
    __shared__ __align__(16) unsigned short As[128][LDSS];
    __shared__ __align__(16) unsigned short Bs[128][LDSS];
    const int n0 = (int)blockIdx.x * 128;
    const int m0 = (int)blockIdx.y * 128;
    const int t = threadIdx.x, lane = t & 63, wave = t >> 6;
    const int wm = (wave & 1) * 64, wn = (wave >> 1) * 64;
    const int ml = lane & 15, q = lane >> 4;
    f32x4 acc[4][4];
#pragma unroll
    for (int i = 0; i < 4; ++i)
#pragma unroll
        for (int j = 0; j < 4; ++j) acc[i][j] = (f32x4){0.f,0.f,0.f,0.f};
    const int sr = t >> 3, sc = (t & 7) * 4;
    for (int kk = 0; kk < K; kk += 32) {
#pragma unroll
        for (int p = 0; p < 4; ++p) {
            int r = sr + p * 32;
            float4 va = *(const float4*)&A[(size_t)(m0 + r) * K + kk + sc];
            ushort4 h; h.x = f2bf(va.x); h.y = f2bf(va.y); h.z = f2bf(va.z); h.w = f2bf(va.w);
            *(ushort4*)&As[r][sc] = h;
            ushort4 vb = *(const ushort4*)&Bw[(size_t)(n0 + r) * K + kk + sc];
            *(ushort4*)&Bs[r][sc] = vb;
        }
        __syncthreads();
        bf16x8 af[4], bf[4];
#pragma unroll
        for (int i = 0; i < 4; ++i) af[i] = *(const bf16x8*)&As[wm + i * 16 + ml][q * 8];
#pragma unroll
        for (int j = 0; j < 4; ++j) bf[j] = *(const bf16x8*)&Bs[wn + j * 16 + ml][q * 8];
#pragma unroll
        for (int i = 0; i < 4; ++i)
#pragma unroll
            for (int j = 0; j < 4; ++j)
                acc[i][j] = __builtin_amdgcn_mfma_f32_16x16x32_bf16(af[i], bf[j], acc[i][j], 0, 0, 0);
        __syncthreads();
    }
    float vw[4];
#pragma unroll
    for (int j = 0; j < 4; ++j) vw[j] = v[n0 + wn + j * 16 + ml];
#pragma unroll
    for (int i = 0; i < 4; ++i)
#pragma unroll
        for (int r = 0; r < 4; ++r) {
            float val = 0.f;
#pragma unroll
            for (int j = 0; j < 4; ++j) val += fast_tanh(acc[i][j][r]) * vw[j];
#pragma unroll
            for (int off = 8; off > 0; off >>= 1) val += __shfl_xor(val, off, 64);
            if (ml == 0) atomicAdd(&score[m0 + wm + i * 16 + q * 4 + r], val);
        }
}

// ---------------- K4: softmax over compact scores, scatter alpha ----------------
__global__ __launch_bounds__(256)
void softmax_compact(const float* __restrict__ score, const unsigned short* __restrict__ ridx,
                     const int* __restrict__ cnt, float* __restrict__ alpha) {
    int b = blockIdx.x, t = threadIdx.x;
    int c = cnt[b];
    __shared__ float red[8];
    float sc[8];
    float mx = -1e30f;
#pragma unroll
    for (int i = 0; i < 8; ++i) {
        int k = i * 256 + t;
        sc[i] = (k < c) ? score[b * 2048 + k] : -1e30f;
        mx = fmaxf(mx, sc[i]);
    }
#pragma unroll
    for (int off = 32; off > 0; off >>= 1)
        mx = fmaxf(mx, __shfl_xor(mx, off, 64));
    if ((t & 63) == 0) red[t >> 6] = mx;
    __syncthreads();
    mx = fmaxf(fmaxf(red[0], red[1]), fmaxf(red[2], red[3]));
    float e[8], sum = 0.f;
#pragma unroll
    for (int i = 0; i < 8; ++i) {
        int k = i * 256 + t;
        e[i] = (k < c) ? __expf(sc[i] - mx) : 0.f;
        sum += e[i];
    }
#pragma unroll
    for (int off = 32; off > 0; off >>= 1)
        sum += __shfl_xor(sum, off, 64);
    if ((t & 63) == 0) red[4 + (t >> 6)] = sum;
    __syncthreads();
    float inv = 1.0f / (red[4] + red[5] + red[6] + red[7]);
#pragma unroll
    for (int i = 0; i < 8; ++i) {
        int k = i * 256 + t;
        if (k < c) {
            int s = ridx[b * 2048 + k];
            alpha[b * 2048 + s] = e[i] * inv;
        }
    }
}

// ---------------- K4-fallback: masked softmax (full rows) ----------------
__global__ __launch_bounds__(256)
void softmax_kernel(const float* __restrict__ score, const int* __restrict__ mask,
                    float* __restrict__ alpha) {
    const int S = 2048;
    int b = blockIdx.x, t = threadIdx.x;
    __shared__ float red[8];
    float sc[8]; int vd[8];
    float mx = -1e30f;
#pragma unroll
    for (int i = 0; i < 8; ++i) {
        int s = i * 256 + t;
        vd[i] = mask[b * S + s];
        sc[i] = score[b * S + s];
        if (vd[i]) mx = fmaxf(mx, sc[i]);
    }
#pragma unroll
    for (int off = 32; off > 0; off >>= 1)
        mx = fmaxf(mx, __shfl_xor(mx, off, 64));
    if ((t & 63) == 0) red[t >> 6] = mx;
    __syncthreads();
    mx = fmaxf(fmaxf(red[0], red[1]), fmaxf(red[2], red[3]));
    float e[8]; float sum = 0.f;
#pragma unroll
    for (int i = 0; i < 8; ++i) {
        e[i] = vd[i] ? __expf(sc[i] - mx) : 0.f;
        sum += e[i];
    }
#pragma unroll
    for (int off = 32; off > 0; off >>= 1)
        sum += __shfl_xor(sum, off, 64);
    if ((t & 63) == 0) red[4 + (t >> 6)] = sum;
    __syncthreads();
    float inv = 1.0f / (red[4] + red[5] + red[6] + red[7]);
#pragma unroll
    for (int i = 0; i < 8; ++i)
        alpha[b * S + i * 256 + t] = e[i] * inv;
}

// ---------------- K5: out[b,:] += sum_s alpha[b,s] * lhs[b,s,:] ----------------
__global__ __launch_bounds__(256)
void wsum_kernel(const float* __restrict__ lhs, const float* __restrict__ alpha,
                 float* __restrict__ out) {
    const int S = 2048, E = 1024;
    int b = blockIdx.x >> 6;
    int seg = blockIdx.x & 63;
    int t = threadIdx.x;
    int s0 = seg * 32;
    const float* base = lhs + ((size_t)b * S + s0) * E + t * 4;
    const float* ap = alpha + b * S + s0;
    float4 acc = {0.f, 0.f, 0.f, 0.f};
#pragma unroll 4
    for (int s = 0; s < 32; ++s) {
        float a = ap[s];
        if (a != 0.f) {
            float4 x = *(const float4*)(base + (size_t)s * E);
            acc.x += a * x.x; acc.y += a * x.y; acc.z += a * x.z; acc.w += a * x.w;
        }
    }
    float* o = out + b * E + t * 4;
    atomicAdd(o + 0, acc.x);
    atomicAdd(o + 1, acc.y);
    atomicAdd(o + 2, acc.z);
    atomicAdd(o + 3, acc.w);
}

extern "C" void kernel_launch(void* const* d_in, const int* in_sizes, int n_in,
                              void* d_out, int out_size, void* d_ws, size_t ws_size,
                              hipStream_t stream) {
    const float* lhs  = (const float*)d_in[0];
    const int*   mask = (const int*)d_in[1];
    const float* W    = (const float*)d_in[2];
    const float* Um   = (const float*)d_in[3];
    const float* v    = (const float*)d_in[4];
    float* out = (float*)d_out;

    char* ws = (char*)d_ws;
    unsigned short* wsum  = (unsigned short*)ws;                      // 2 MB
    float* score          = (float*)(ws + 2048u * 1024u);             // 256 KB
    float* alpha          = (float*)(ws + 2304u * 1024u);             // 256 KB
    unsigned short* ridx  = (unsigned short*)(ws + 2560u * 1024u);    // 128 KB
    int* cnt              = (int*)(ws + 2688u * 1024u);               // 128 B
    unsigned short* Ab    = (unsigned short*)(ws + 2816u * 1024u);    // 128 MB
    const size_t need = 2816ull * 1024ull + 65536ull * 1024ull * 2ull;

    prep_kernel<<<1024, 256, 0, stream>>>(W, Um, wsum, score, alpha, out);
    if (ws_size >= need) {
        index_kernel<<<32, 256, 0, stream>>>(mask, ridx, cnt);
        dim3 gg(512, 32);
        gather_convert<<<gg, 256, 0, stream>>>(lhs, ridx, cnt, Ab);
        dim3 g1(8, 512);
        score_gemm_bf16<<<g1, 256, 0, stream>>>(Ab, wsum, v, cnt, score);
        softmax_compact<<<32, 256, 0, stream>>>(score, ridx, cnt, alpha);
    } else {
        dim3 g1(8, 512);
        score_gemm_f32stage<<<g1, 256, 0, stream>>>(lhs, wsum, v, score);
        softmax_kernel<<<32, 256, 0, stream>>>(score, mask, alpha);
    }
    wsum_kernel<<<2048, 256, 0, stream>>>(lhs, alpha, out);
}